// Round 2
// baseline (344.224 us; speedup 1.0000x reference)
//
#include <hip/hip_runtime.h>
#include <hip/hip_bf16.h>
#include <stdint.h>

#define F_DIM 256
#define H_DIM 384
#define L_DIM 64
#define O_DIM 16
#define E_NUM 5
#define BM 32

#define H_STRIDE 392   // bf16 elems (384 + 8 pad)
#define LAT_STRIDE 33  // f32 elems (32 + 1 pad)
#define MU_STRIDE 328  // bf16 elems (320 + 8 pad)

typedef short bf16x8 __attribute__((ext_vector_type(8)));
typedef float f32x4 __attribute__((ext_vector_type(4)));

__device__ __forceinline__ unsigned short f2bf(float f) {
    union { float f; unsigned int u; } v; v.f = f;
    unsigned int u = v.u;
    return (unsigned short)((u + 0x7FFFu + ((u >> 16) & 1u)) >> 16);
}

__device__ __forceinline__ float sigmoidf(float x) {
    return 1.0f / (1.0f + __expf(-x));
}

// ---- prep: W1 (256x384) -> W1T bf16 (384x256); W2 (384x64) -> W2T bf16 (64x384);
//      pi (5x64x16) -> piT bf16 (16x320), pre-scaled by 1/E.
__global__ void prep_kernel(const float* __restrict__ W1, const float* __restrict__ W2,
                            const float* __restrict__ pi,
                            unsigned short* __restrict__ W1T,
                            unsigned short* __restrict__ W2T,
                            unsigned short* __restrict__ piT) {
    int idx = blockIdx.x * blockDim.x + threadIdx.x;
    if (idx < H_DIM * F_DIM) {
        int n = idx / F_DIM, k = idx % F_DIM;
        W1T[idx] = f2bf(W1[k * H_DIM + n]);
    }
    int i2 = idx - H_DIM * F_DIM;
    if (i2 >= 0 && i2 < L_DIM * H_DIM) {
        int l = i2 / H_DIM, h = i2 % H_DIM;
        W2T[i2] = f2bf(W2[h * L_DIM + l]);
    }
    int i3 = i2 - L_DIM * H_DIM;
    if (i3 >= 0 && i3 < O_DIM * E_NUM * L_DIM) {
        int o = i3 / (E_NUM * L_DIM), el = i3 % (E_NUM * L_DIM);
        piT[i3] = f2bf(pi[el * O_DIM + o] * 0.2f);
    }
}

__global__ __launch_bounds__(256, 3) void fused_kernel(
    const float* __restrict__ X,
    const unsigned short* __restrict__ W1T,
    const float* __restrict__ b1,
    const unsigned short* __restrict__ W2T,
    const float* __restrict__ b2,
    const int* __restrict__ phi,
    const unsigned short* __restrict__ piT,
    float* __restrict__ out) {

    __shared__ unsigned short Hs[BM * H_STRIDE];      // 25088 B, h tile bf16 [m][n]
    __shared__ float latT[L_DIM * LAT_STRIDE];        // 8448 B, latent [l][m]
    __shared__ int phis[E_NUM * L_DIM];               // 1280 B
    unsigned short* mus = Hs;                          // mu [m][e*64+l] bf16, aliases Hs (20992 B <= 25088)

    const int tid  = threadIdx.x;
    const int wave = tid >> 6;
    const int lane = tid & 63;
    const int q    = lane >> 4;   // 0..3
    const int c    = lane & 15;   // 0..15
    const int row0 = blockIdx.x * BM;

    // E_NUM*L_DIM = 320 > blockDim = 256: MUST grid-stride (was the e=4 corruption bug)
    for (int idx = tid; idx < E_NUM * L_DIM; idx += 256) phis[idx] = phi[idx];

    // ================= GEMM1: D[n][m] = sum_k W1T[n][k] * X[m][k] =================
    // wave owns n-strip [wave*96, wave*96+96): 6 n-tiles x 2 m-tiles
    f32x4 acc[6][2];
    #pragma unroll
    for (int i = 0; i < 6; ++i)
        #pragma unroll
        for (int j = 0; j < 2; ++j)
            acc[i][j] = (f32x4){0.f, 0.f, 0.f, 0.f};

    const int nbase = wave * 96;
    #pragma unroll
    for (int ks = 0; ks < 8; ++ks) {
        bf16x8 afrag[6];
        #pragma unroll
        for (int i = 0; i < 6; ++i) {
            const unsigned short* p = W1T + (nbase + i * 16 + c) * F_DIM + ks * 32 + q * 8;
            afrag[i] = *(const bf16x8*)p;
        }
        bf16x8 bfrag[2];
        #pragma unroll
        for (int j = 0; j < 2; ++j) {
            const float* p = X + (size_t)(row0 + j * 16 + c) * F_DIM + ks * 32 + q * 8;
            float4 x0 = *(const float4*)p;
            float4 x1 = *(const float4*)(p + 4);
            bf16x8 b;
            b[0] = (short)f2bf(x0.x); b[1] = (short)f2bf(x0.y);
            b[2] = (short)f2bf(x0.z); b[3] = (short)f2bf(x0.w);
            b[4] = (short)f2bf(x1.x); b[5] = (short)f2bf(x1.y);
            b[6] = (short)f2bf(x1.z); b[7] = (short)f2bf(x1.w);
            bfrag[j] = b;
        }
        #pragma unroll
        for (int i = 0; i < 6; ++i)
            #pragma unroll
            for (int j = 0; j < 2; ++j)
                acc[i][j] = __builtin_amdgcn_mfma_f32_16x16x32_bf16(afrag[i], bfrag[j], acc[i][j], 0, 0, 0);
    }
    // epilogue: lane holds n = nbase + i*16 + q*4 + reg (4 consecutive), m = j*16 + c
    #pragma unroll
    for (int i = 0; i < 6; ++i) {
        const int n0 = nbase + i * 16 + q * 4;
        float4 bv = *(const float4*)(b1 + n0);
        #pragma unroll
        for (int j = 0; j < 2; ++j) {
            const int m = j * 16 + c;
            ushort4 h4;
            h4.x = f2bf(sigmoidf(acc[i][j][0] + bv.x));
            h4.y = f2bf(sigmoidf(acc[i][j][1] + bv.y));
            h4.z = f2bf(sigmoidf(acc[i][j][2] + bv.z));
            h4.w = f2bf(sigmoidf(acc[i][j][3] + bv.w));
            *((ushort4*)&Hs[m * H_STRIDE + n0]) = h4;   // 8B aligned: 784*m + 8*(n0/4)
        }
    }
    __syncthreads();

    // ================= GEMM2: D[l][m] = sum_h W2T[l][h] * Hs[m][h] =================
    {
        f32x4 acc2[2];
        acc2[0] = (f32x4){0.f, 0.f, 0.f, 0.f};
        acc2[1] = (f32x4){0.f, 0.f, 0.f, 0.f};
        const int lb = wave * 16;   // wave owns one l-tile, both m-tiles
        #pragma unroll
        for (int ks = 0; ks < 12; ++ks) {
            const unsigned short* pa = W2T + (lb + c) * H_DIM + ks * 32 + q * 8;
            bf16x8 af = *(const bf16x8*)pa;
            #pragma unroll
            for (int j = 0; j < 2; ++j) {
                bf16x8 bf_ = *((const bf16x8*)&Hs[(j * 16 + c) * H_STRIDE + ks * 32 + q * 8]);
                acc2[j] = __builtin_amdgcn_mfma_f32_16x16x32_bf16(af, bf_, acc2[j], 0, 0, 0);
            }
        }
        const float4 b2v = *(const float4*)(b2 + lb + q * 4);
        #pragma unroll
        for (int j = 0; j < 2; ++j) {
            const int m = j * 16 + c;
            #pragma unroll
            for (int rg = 0; rg < 4; ++rg) {
                const int l = lb + q * 4 + rg;
                latT[l * LAT_STRIDE + m] = sigmoidf(acc2[j][rg] + ((const float*)&b2v)[rg]);
            }
        }
    }
    __syncthreads();   // latT complete; Hs dead -> mus may be written

    // ================= stage 3a: tree routing, mu -> LDS bf16 =================
    {
        const int r = lane & 31;
        const int e = wave * 2 + (lane >> 5);
        if (e < E_NUM) {
            float mu[64];
            mu[0] = 1.0f;
            #pragma unroll
            for (int lev = 0; lev < 6; ++lev) {
                const int w = 1 << lev;
                #pragma unroll
                for (int i = w - 1; i >= 0; --i) {
                    float d = latT[phis[e * 64 + w + i] * LAT_STRIDE + r];
                    float m = mu[i];
                    mu[2 * i + 1] = m - m * d;   // m*(1-d)
                    mu[2 * i]     = m * d;
                }
            }
            #pragma unroll
            for (int j8 = 0; j8 < 8; ++j8) {
                bf16x8 v;
                #pragma unroll
                for (int t = 0; t < 8; ++t) v[t] = (short)f2bf(mu[j8 * 8 + t]);
                *((bf16x8*)&mus[r * MU_STRIDE + e * 64 + j8 * 8]) = v;
            }
        }
    }
    __syncthreads();

    // ================= stage 3b: out[m][o] = sum_k mu[m][k] * piT[o][k] =================
    if (wave < 2) {
        f32x4 acc3 = (f32x4){0.f, 0.f, 0.f, 0.f};
        const int mt = wave;
        #pragma unroll
        for (int ks = 0; ks < 10; ++ks) {
            bf16x8 af  = *((const bf16x8*)&mus[(mt * 16 + c) * MU_STRIDE + ks * 32 + q * 8]);
            bf16x8 bf_ = *(const bf16x8*)(piT + c * 320 + ks * 32 + q * 8);
            acc3 = __builtin_amdgcn_mfma_f32_16x16x32_bf16(af, bf_, acc3, 0, 0, 0);
        }
        #pragma unroll
        for (int rg = 0; rg < 4; ++rg) {
            const int m = mt * 16 + q * 4 + rg;
            out[(size_t)(row0 + m) * O_DIM + c] = acc3[rg];
        }
    }
}

extern "C" void kernel_launch(void* const* d_in, const int* in_sizes, int n_in,
                              void* d_out, int out_size, void* d_ws, size_t ws_size,
                              hipStream_t stream) {
    (void)in_sizes; (void)n_in; (void)out_size; (void)ws_size;
    const float* X  = (const float*)d_in[0];
    const float* W1 = (const float*)d_in[1];
    const float* b1 = (const float*)d_in[2];
    const float* W2 = (const float*)d_in[3];
    const float* b2 = (const float*)d_in[4];
    const int*   phi = (const int*)d_in[5];
    const float* pi  = (const float*)d_in[6];
    float* out = (float*)d_out;

    unsigned short* W1T = (unsigned short*)d_ws;                         // 384*256*2 = 196608 B
    unsigned short* W2T = (unsigned short*)((char*)d_ws + 196608);       // 64*384*2  =  49152 B
    unsigned short* piT = (unsigned short*)((char*)d_ws + 196608 + 49152); // 16*320*2 = 10240 B

    const int prep_elems = H_DIM * F_DIM + L_DIM * H_DIM + O_DIM * E_NUM * L_DIM; // 128000
    prep_kernel<<<(prep_elems + 255) / 256, 256, 0, stream>>>(W1, W2, pi, W1T, W2T, piT);

    const int nblocks = 131072 / BM;  // 4096
    fused_kernel<<<nblocks, 256, 0, stream>>>(X, W1T, b1, W2T, b2, phi, piT, out);
}

// Round 3
// 317.194 us; speedup vs baseline: 1.0852x; 1.0852x over previous
//
#include <hip/hip_runtime.h>
#include <hip/hip_bf16.h>
#include <stdint.h>

#define F_DIM 256
#define H_DIM 384
#define L_DIM 64
#define O_DIM 16
#define E_NUM 5
#define BM 32

#define XK_STRIDE 264   // bf16 elems (256 + 8 pad)  -> 528 B/row
#define H_STRIDE 392    // bf16 elems (384 + 8 pad)  -> 784 B/row
#define LAT_STRIDE 33   // f32 elems (32 + 1 pad)
#define MU_STRIDE 328   // bf16 elems (320 + 8 pad)

typedef short bf16x8 __attribute__((ext_vector_type(8)));
typedef float f32x4 __attribute__((ext_vector_type(4)));

__device__ __forceinline__ unsigned short f2bf(float f) {
    union { float f; unsigned int u; } v; v.f = f;
    unsigned int u = v.u;
    return (unsigned short)((u + 0x7FFFu + ((u >> 16) & 1u)) >> 16);
}

// pack float2 -> bf16x2 (one dword), RNE
__device__ __forceinline__ unsigned int pk2(float a, float b) {
#if defined(__has_builtin)
#if __has_builtin(__builtin_amdgcn_cvt_pk_bf16_f32)
    typedef __bf16 bf2 __attribute__((ext_vector_type(2)));
    bf2 p = __builtin_amdgcn_cvt_pk_bf16_f32(a, b);
    union { bf2 v; unsigned int u; } c; c.v = p;
    return c.u;
#else
    return (unsigned int)f2bf(a) | ((unsigned int)f2bf(b) << 16);
#endif
#else
    return (unsigned int)f2bf(a) | ((unsigned int)f2bf(b) << 16);
#endif
}

__device__ __forceinline__ uint2 cvt4(float4 v) {
    uint2 r; r.x = pk2(v.x, v.y); r.y = pk2(v.z, v.w); return r;
}

// fast sigmoid: v_exp_f32 + v_rcp_f32 (~1 ulp each; stored to bf16 anyway)
__device__ __forceinline__ float sigmoidf(float x) {
    return __builtin_amdgcn_rcpf(1.0f + __builtin_amdgcn_exp2f(-1.44269504088896f * x));
}

// ---- prep: coalesced LDS-tile transposes.
// blocks 0..95:   W1 (256x384) -> W1T bf16 (384x256)
// blocks 96..119: W2 (384x64)  -> W2T bf16 (64x384)
// block 120:      pi (5x64x16) -> piT bf16 (16x320), pre-scaled 1/E
__global__ void prep_kernel(const float* __restrict__ W1, const float* __restrict__ W2,
                            const float* __restrict__ pi,
                            unsigned short* __restrict__ W1T,
                            unsigned short* __restrict__ W2T,
                            unsigned short* __restrict__ piT) {
    __shared__ float tile[32][33];
    const int b = blockIdx.x;
    const int tx = threadIdx.x & 31, ty = threadIdx.x >> 5;  // ty 0..7
    if (b < 96) {
        const int fb = b / 12, hb = b % 12;
        #pragma unroll
        for (int s = 0; s < 32; s += 8)
            tile[ty + s][tx] = W1[(size_t)(fb * 32 + ty + s) * H_DIM + hb * 32 + tx];
        __syncthreads();
        #pragma unroll
        for (int s = 0; s < 32; s += 8)
            W1T[(size_t)(hb * 32 + ty + s) * F_DIM + fb * 32 + tx] = f2bf(tile[tx][ty + s]);
    } else if (b < 120) {
        const int bb = b - 96, hb = bb / 2, lb = bb % 2;
        #pragma unroll
        for (int s = 0; s < 32; s += 8)
            tile[ty + s][tx] = W2[(size_t)(hb * 32 + ty + s) * L_DIM + lb * 32 + tx];
        __syncthreads();
        #pragma unroll
        for (int s = 0; s < 32; s += 8)
            W2T[(size_t)(lb * 32 + ty + s) * H_DIM + hb * 32 + tx] = f2bf(tile[tx][ty + s]);
    } else {
        for (int i = threadIdx.x; i < O_DIM * E_NUM * L_DIM; i += 256) {
            int o = i / 320, el = i % 320;
            piT[i] = f2bf(pi[el * O_DIM + o] * 0.2f);
        }
    }
}

__global__ __launch_bounds__(256, 4) void fused_kernel(
    const float* __restrict__ X,
    const unsigned short* __restrict__ W1T,
    const float* __restrict__ b1,
    const unsigned short* __restrict__ W2T,
    const float* __restrict__ b2,
    const int* __restrict__ phi,
    const unsigned short* __restrict__ piT,
    float* __restrict__ out) {

    __shared__ __align__(16) unsigned char smem[34816];
    unsigned short* Xs  = (unsigned short*)smem;            // [32][264] 16896 B (dead after GEMM1 reads)
    unsigned short* Hs  = (unsigned short*)smem;            // [32][392] 25088 B (written after B2)
    float*          latT = (float*)(smem + 25088);          // [64][33]   8448 B
    int*            phis = (int*)(smem + 33536);            // 320*4      1280 B  -> 34816 total
    unsigned short* mus = (unsigned short*)smem;            // [32][328] 20992 B (after Hs dead)

    const int tid  = threadIdx.x;
    const int wave = tid >> 6;
    const int lane = tid & 63;
    const int q    = lane >> 4;   // 0..3
    const int c    = lane & 15;   // 0..15
    const int row0 = blockIdx.x * BM;

    // ---- stage X tile: 8 coalesced row loads per wave, convert once, bf16 -> LDS
    float4 f4[8];
    #pragma unroll
    for (int i = 0; i < 8; ++i)
        f4[i] = *(const float4*)(X + (size_t)(row0 + wave * 8 + i) * F_DIM + lane * 4);

    for (int idx = tid; idx < E_NUM * L_DIM; idx += 256) phis[idx] = phi[idx];

    #pragma unroll
    for (int i = 0; i < 8; ++i) {
        uint2 r = cvt4(f4[i]);
        *(uint2*)&Xs[(wave * 8 + i) * XK_STRIDE + lane * 4] = r;
    }

    // prefetch ks=0 A-fragments (global, independent of LDS) before the barrier
    const int nbase = wave * 96;
    bf16x8 af0[6];
    #pragma unroll
    for (int i = 0; i < 6; ++i)
        af0[i] = *(const bf16x8*)(W1T + (size_t)(nbase + i * 16 + c) * F_DIM + q * 8);

    __syncthreads();   // B1: Xs + phis ready

    // ================= GEMM1: D[n][m] = sum_k W1T[n][k] * Xs[m][k] =================
    f32x4 acc[6][2];
    #pragma unroll
    for (int i = 0; i < 6; ++i)
        #pragma unroll
        for (int j = 0; j < 2; ++j)
            acc[i][j] = (f32x4){0.f, 0.f, 0.f, 0.f};

    {   // ks = 0 (peeled, uses prefetched af0)
        bf16x8 bf0[2];
        #pragma unroll
        for (int j = 0; j < 2; ++j)
            bf0[j] = *(const bf16x8*)&Xs[(j * 16 + c) * XK_STRIDE + q * 8];
        #pragma unroll
        for (int i = 0; i < 6; ++i)
            #pragma unroll
            for (int j = 0; j < 2; ++j)
                acc[i][j] = __builtin_amdgcn_mfma_f32_16x16x32_bf16(af0[i], bf0[j], acc[i][j], 0, 0, 0);
    }
    #pragma unroll 2
    for (int ks = 1; ks < 8; ++ks) {
        bf16x8 af[6];
        #pragma unroll
        for (int i = 0; i < 6; ++i)
            af[i] = *(const bf16x8*)(W1T + (size_t)(nbase + i * 16 + c) * F_DIM + ks * 32 + q * 8);
        bf16x8 bf_[2];
        #pragma unroll
        for (int j = 0; j < 2; ++j)
            bf_[j] = *(const bf16x8*)&Xs[(j * 16 + c) * XK_STRIDE + ks * 32 + q * 8];
        #pragma unroll
        for (int i = 0; i < 6; ++i)
            #pragma unroll
            for (int j = 0; j < 2; ++j)
                acc[i][j] = __builtin_amdgcn_mfma_f32_16x16x32_bf16(af[i], bf_[j], acc[i][j], 0, 0, 0);
    }
    __syncthreads();   // B2: all Xs reads done; Hs (aliases Xs) may now be written

    // epilogue: lane holds n = nbase + i*16 + q*4 + reg, m = j*16 + c
    #pragma unroll
    for (int i = 0; i < 6; ++i) {
        const int n0 = nbase + i * 16 + q * 4;
        float4 bv = *(const float4*)(b1 + n0);
        #pragma unroll
        for (int j = 0; j < 2; ++j) {
            const int m = j * 16 + c;
            uint2 h2;
            h2.x = pk2(sigmoidf(acc[i][j][0] + bv.x), sigmoidf(acc[i][j][1] + bv.y));
            h2.y = pk2(sigmoidf(acc[i][j][2] + bv.z), sigmoidf(acc[i][j][3] + bv.w));
            *(uint2*)&Hs[m * H_STRIDE + n0] = h2;
        }
    }
    __syncthreads();   // B3: Hs complete

    // ================= GEMM2: D[l][m] = sum_h W2T[l][h] * Hs[m][h] =================
    {
        const int lb = wave * 16;
        bf16x8 wfrag[12];
        #pragma unroll
        for (int ks = 0; ks < 12; ++ks)
            wfrag[ks] = *(const bf16x8*)(W2T + (size_t)(lb + c) * H_DIM + ks * 32 + q * 8);
        f32x4 acc2[2];
        acc2[0] = (f32x4){0.f, 0.f, 0.f, 0.f};
        acc2[1] = (f32x4){0.f, 0.f, 0.f, 0.f};
        #pragma unroll
        for (int ks = 0; ks < 12; ++ks) {
            #pragma unroll
            for (int j = 0; j < 2; ++j) {
                bf16x8 bf_ = *(const bf16x8*)&Hs[(j * 16 + c) * H_STRIDE + ks * 32 + q * 8];
                acc2[j] = __builtin_amdgcn_mfma_f32_16x16x32_bf16(wfrag[ks], bf_, acc2[j], 0, 0, 0);
            }
        }
        const float4 b2v = *(const float4*)(b2 + lb + q * 4);
        #pragma unroll
        for (int j = 0; j < 2; ++j) {
            const int m = j * 16 + c;
            #pragma unroll
            for (int rg = 0; rg < 4; ++rg) {
                const int l = lb + q * 4 + rg;
                latT[l * LAT_STRIDE + m] = sigmoidf(acc2[j][rg] + ((const float*)&b2v)[rg]);
            }
        }
    }
    __syncthreads();   // B4: latT complete; Hs dead -> mus may be written

    // ================= stage 3a: tree routing, mu -> LDS bf16 =================
    {
        const int r = lane & 31;
        const int e = wave * 2 + (lane >> 5);
        if (e < E_NUM) {
            float mu[64];
            mu[0] = 1.0f;
            #pragma unroll
            for (int lev = 0; lev < 6; ++lev) {
                const int w = 1 << lev;
                #pragma unroll
                for (int i = w - 1; i >= 0; --i) {
                    float d = latT[phis[e * 64 + w + i] * LAT_STRIDE + r];
                    float m = mu[i];
                    mu[2 * i + 1] = m - m * d;   // m*(1-d)
                    mu[2 * i]     = m * d;
                }
            }
            #pragma unroll
            for (int j8 = 0; j8 < 8; ++j8) {
                bf16x8 v;
                #pragma unroll
                for (int t = 0; t < 4; ++t) {
                    unsigned int p = pk2(mu[j8 * 8 + 2 * t], mu[j8 * 8 + 2 * t + 1]);
                    v[2 * t]     = (short)(p & 0xFFFF);
                    v[2 * t + 1] = (short)(p >> 16);
                }
                *((bf16x8*)&mus[r * MU_STRIDE + e * 64 + j8 * 8]) = v;
            }
        }
    }
    __syncthreads();   // B5: mus complete

    // ================= stage 3b: out[m][o] = sum_k mus[m][k] * piT[o][k] =================
    if (wave < 2) {
        const int mt = wave;
        bf16x8 pfrag[10];
        #pragma unroll
        for (int ks = 0; ks < 10; ++ks)
            pfrag[ks] = *(const bf16x8*)(piT + c * 320 + ks * 32 + q * 8);
        f32x4 acc3 = (f32x4){0.f, 0.f, 0.f, 0.f};
        #pragma unroll
        for (int ks = 0; ks < 10; ++ks) {
            bf16x8 af = *((const bf16x8*)&mus[(mt * 16 + c) * MU_STRIDE + ks * 32 + q * 8]);
            acc3 = __builtin_amdgcn_mfma_f32_16x16x32_bf16(af, pfrag[ks], acc3, 0, 0, 0);
        }
        #pragma unroll
        for (int rg = 0; rg < 4; ++rg) {
            const int m = mt * 16 + q * 4 + rg;
            out[(size_t)(row0 + m) * O_DIM + c] = acc3[rg];
        }
    }
}

extern "C" void kernel_launch(void* const* d_in, const int* in_sizes, int n_in,
                              void* d_out, int out_size, void* d_ws, size_t ws_size,
                              hipStream_t stream) {
    (void)in_sizes; (void)n_in; (void)out_size; (void)ws_size;
    const float* X  = (const float*)d_in[0];
    const float* W1 = (const float*)d_in[1];
    const float* b1 = (const float*)d_in[2];
    const float* W2 = (const float*)d_in[3];
    const float* b2 = (const float*)d_in[4];
    const int*   phi = (const int*)d_in[5];
    const float* pi  = (const float*)d_in[6];
    float* out = (float*)d_out;

    unsigned short* W1T = (unsigned short*)d_ws;                           // 196608 B
    unsigned short* W2T = (unsigned short*)((char*)d_ws + 196608);         //  49152 B
    unsigned short* piT = (unsigned short*)((char*)d_ws + 196608 + 49152); //  10240 B

    prep_kernel<<<121, 256, 0, stream>>>(W1, W2, pi, W1T, W2T, piT);

    const int nblocks = 131072 / BM;  // 4096
    fused_kernel<<<nblocks, 256, 0, stream>>>(X, W1T, b1, W2T, b2, phi, piT, out);
}

// Round 4
// 248.729 us; speedup vs baseline: 1.3839x; 1.2753x over previous
//
#include <hip/hip_runtime.h>
#include <hip/hip_bf16.h>
#include <stdint.h>

#define F_DIM 256
#define H_DIM 384
#define L_DIM 64
#define O_DIM 16
#define E_NUM 5
#define BM 32

#define XK_STRIDE 264   // bf16 elems (256 + 8 pad)
#define H_STRIDE 392    // bf16 elems (384 + 8 pad)
#define LAT_STRIDE 33   // f32 elems (32 + 1 pad)
#define MU_STRIDE 328   // bf16 elems (320 + 8 pad)

typedef short bf16x8 __attribute__((ext_vector_type(8)));
typedef float f32x4 __attribute__((ext_vector_type(4)));

__device__ __forceinline__ unsigned short f2bf(float f) {
    union { float f; unsigned int u; } v; v.f = f;
    unsigned int u = v.u;
    return (unsigned short)((u + 0x7FFFu + ((u >> 16) & 1u)) >> 16);
}

__device__ __forceinline__ unsigned int pk2(float a, float b) {
#if defined(__has_builtin)
#if __has_builtin(__builtin_amdgcn_cvt_pk_bf16_f32)
    typedef __bf16 bf2 __attribute__((ext_vector_type(2)));
    bf2 p = __builtin_amdgcn_cvt_pk_bf16_f32(a, b);
    union { bf2 v; unsigned int u; } c; c.v = p;
    return c.u;
#else
    return (unsigned int)f2bf(a) | ((unsigned int)f2bf(b) << 16);
#endif
#else
    return (unsigned int)f2bf(a) | ((unsigned int)f2bf(b) << 16);
#endif
}

__device__ __forceinline__ uint2 cvt4(float4 v) {
    uint2 r; r.x = pk2(v.x, v.y); r.y = pk2(v.z, v.w); return r;
}

__device__ __forceinline__ float sigmoidf(float x) {
    return __builtin_amdgcn_rcpf(1.0f + __builtin_amdgcn_exp2f(-1.44269504088896f * x));
}

// ============================ prep ============================
// Weights are written in MFMA A-fragment order:
//   Wf[tile][ks][lane][8]  (tile = 16 output-rows, ks = 32 k's, lane = q*16+c)
//   element j of lane (q,c) = W^T[tile*16 + c][ks*32 + q*8 + j]
// so the fused kernel's fragment load is  base + lane*16B + const  (coalesced 1KB/wave).
// blocks 0..95:   W1 (256x384 f,h) -> W1f (24 tiles, 8 ks)
// blocks 96..119: W2 (384x64  h,l) -> W2f (4 tiles, 12 ks)
// block 120:      pi (5x64x16)     -> piTf (1 tile... 16 rows, 10 ks), pre-scaled 1/E
__global__ void prep_kernel(const float* __restrict__ W1, const float* __restrict__ W2,
                            const float* __restrict__ pi,
                            unsigned short* __restrict__ W1f,
                            unsigned short* __restrict__ W2f,
                            unsigned short* __restrict__ piTf) {
    __shared__ float tile[32][33];   // [k_local][row_local]
    const int b = blockIdx.x;
    const int tid = threadIdx.x;
    const int tx = tid & 31, ty = tid >> 5;  // ty 0..7

    if (b < 120) {
        int ks, t0, nks;
        unsigned short* dst;
        if (b < 96) {
            const int fb = b / 12, hb = b % 12;       // k-tile, row-tile-pair
            #pragma unroll
            for (int s = 0; s < 32; s += 8)
                tile[ty + s][tx] = W1[(size_t)(fb * 32 + ty + s) * H_DIM + hb * 32 + tx];
            ks = fb; t0 = hb * 2; nks = 8; dst = W1f;
        } else {
            const int bb = b - 96, hb = bb / 2, lb = bb % 2;
            #pragma unroll
            for (int s = 0; s < 32; s += 8)
                tile[ty + s][tx] = W2[(size_t)(hb * 32 + ty + s) * L_DIM + lb * 32 + tx];
            ks = hb; t0 = lb * 2; nks = 12; dst = W2f;
        }
        __syncthreads();
        // write phase: 512 dwords (1024 shorts); thread writes one uint2 (4 shorts)
        // d = tid*2: t_local = tid/128, r = (tid*2)%256: lane = r/4, e2base = r%4 (0 or 2)
        const int t_local = tid >> 7;
        const int r = (tid * 2) & 255;
        const int lane = r >> 2;
        const int e2b = r & 3;            // 0 or 2
        const int q = lane >> 4, c = lane & 15;
        const int f0 = q * 8 + e2b * 2;   // k_local base (4 consecutive)
        const int hl = t_local * 16 + c;  // row_local
        uint2 v;
        v.x = pk2(tile[f0 + 0][hl], tile[f0 + 1][hl]);
        v.y = pk2(tile[f0 + 2][hl], tile[f0 + 3][hl]);
        const size_t off = ((size_t)((t0 + t_local) * nks + ks) * 64 + lane) * 8 + e2b * 2;
        *(uint2*)(dst + off) = v;
    } else {
        // piTf[ks*512 + lane*8 + j] = pi[k][o]*0.2, o = c, k = ks*32+q*8+j
        for (int i = tid; i < O_DIM * E_NUM * L_DIM; i += 256) {
            const int j = i & 7, lane = (i >> 3) & 63, ks = i >> 9;
            const int q = lane >> 4, c = lane & 15;
            const int k = ks * 32 + q * 8 + j;
            piTf[i] = f2bf(pi[k * O_DIM + c] * 0.2f);
        }
    }
}

// ============================ fused ============================
__global__ __launch_bounds__(256, 3) void fused_kernel(
    const float* __restrict__ X,
    const unsigned short* __restrict__ W1f,
    const float* __restrict__ b1,
    const unsigned short* __restrict__ W2f,
    const float* __restrict__ b2,
    const int* __restrict__ phi,
    const unsigned short* __restrict__ piTf,
    float* __restrict__ out) {

    __shared__ __align__(16) unsigned char smem[34816];
    unsigned short* Xs  = (unsigned short*)smem;            // [32][264] 16896 B
    unsigned short* Hs  = (unsigned short*)smem;            // [32][392] 25088 B (after Xs dead)
    float*          latT = (float*)(smem + 25088);          // [64][33]   8448 B
    int*            phis = (int*)(smem + 33536);            // 1280 B -> 34816 total
    unsigned short* mus = (unsigned short*)smem;            // [32][328] 20992 B (after Hs dead)

    const int tid  = threadIdx.x;
    const int wave = tid >> 6;
    const int lane = tid & 63;
    const int q    = lane >> 4;
    const int c    = lane & 15;
    const int row0 = blockIdx.x * BM;

    for (int idx = tid; idx < E_NUM * L_DIM; idx += 256) phis[idx] = phi[idx];

    // ---- stage X tile in 2 batches of 4 rows (16 live VGPRs, no spill)
    #pragma unroll
    for (int h = 0; h < 2; ++h) {
        float4 t0[4];
        #pragma unroll
        for (int i = 0; i < 4; ++i)
            t0[i] = *(const float4*)(X + (size_t)(row0 + wave * 8 + h * 4 + i) * F_DIM + lane * 4);
        #pragma unroll
        for (int i = 0; i < 4; ++i)
            *(uint2*)&Xs[(wave * 8 + h * 4 + i) * XK_STRIDE + lane * 4] = cvt4(t0[i]);
    }

    // prefetch ks=0 A-fragments (coalesced, 24 VGPRs) to hide behind barrier
    bf16x8 af0[6];
    #pragma unroll
    for (int i = 0; i < 6; ++i)
        af0[i] = *(const bf16x8*)(W1f + ((size_t)(wave * 48 + i * 8 + 0) * 64 + lane) * 8);

    __syncthreads();   // B1: Xs + phis ready

    // ================= GEMM1: D[n][m] = sum_k W1T[n][k] * Xs[m][k] =================
    f32x4 acc[6][2];
    #pragma unroll
    for (int i = 0; i < 6; ++i)
        #pragma unroll
        for (int j = 0; j < 2; ++j)
            acc[i][j] = (f32x4){0.f, 0.f, 0.f, 0.f};

    {   // ks = 0 (peeled)
        bf16x8 bf0[2];
        #pragma unroll
        for (int j = 0; j < 2; ++j)
            bf0[j] = *(const bf16x8*)&Xs[(j * 16 + c) * XK_STRIDE + q * 8];
        #pragma unroll
        for (int i = 0; i < 6; ++i)
            #pragma unroll
            for (int j = 0; j < 2; ++j)
                acc[i][j] = __builtin_amdgcn_mfma_f32_16x16x32_bf16(af0[i], bf0[j], acc[i][j], 0, 0, 0);
    }
    #pragma unroll 2
    for (int ks = 1; ks < 8; ++ks) {
        bf16x8 af[6];
        #pragma unroll
        for (int i = 0; i < 6; ++i)
            af[i] = *(const bf16x8*)(W1f + ((size_t)(wave * 48 + i * 8 + ks) * 64 + lane) * 8);
        bf16x8 bf_[2];
        #pragma unroll
        for (int j = 0; j < 2; ++j)
            bf_[j] = *(const bf16x8*)&Xs[(j * 16 + c) * XK_STRIDE + ks * 32 + q * 8];
        #pragma unroll
        for (int i = 0; i < 6; ++i)
            #pragma unroll
            for (int j = 0; j < 2; ++j)
                acc[i][j] = __builtin_amdgcn_mfma_f32_16x16x32_bf16(af[i], bf_[j], acc[i][j], 0, 0, 0);
    }
    __syncthreads();   // B2: Xs reads done; Hs (aliases) may be written

    const int nbase = wave * 96;
    #pragma unroll
    for (int i = 0; i < 6; ++i) {
        const int n0 = nbase + i * 16 + q * 4;
        float4 bv = *(const float4*)(b1 + n0);
        #pragma unroll
        for (int j = 0; j < 2; ++j) {
            const int m = j * 16 + c;
            uint2 h2;
            h2.x = pk2(sigmoidf(acc[i][j][0] + bv.x), sigmoidf(acc[i][j][1] + bv.y));
            h2.y = pk2(sigmoidf(acc[i][j][2] + bv.z), sigmoidf(acc[i][j][3] + bv.w));
            *(uint2*)&Hs[m * H_STRIDE + n0] = h2;
        }
    }
    __syncthreads();   // B3: Hs complete

    // ================= GEMM2: D[l][m] = sum_h W2T[l][h] * Hs[m][h] =================
    {
        bf16x8 wfrag[12];
        #pragma unroll
        for (int ks = 0; ks < 12; ++ks)
            wfrag[ks] = *(const bf16x8*)(W2f + ((size_t)(wave * 12 + ks) * 64 + lane) * 8);
        f32x4 acc2[2];
        acc2[0] = (f32x4){0.f, 0.f, 0.f, 0.f};
        acc2[1] = (f32x4){0.f, 0.f, 0.f, 0.f};
        #pragma unroll
        for (int ks = 0; ks < 12; ++ks) {
            #pragma unroll
            for (int j = 0; j < 2; ++j) {
                bf16x8 bf_ = *(const bf16x8*)&Hs[(j * 16 + c) * H_STRIDE + ks * 32 + q * 8];
                acc2[j] = __builtin_amdgcn_mfma_f32_16x16x32_bf16(wfrag[ks], bf_, acc2[j], 0, 0, 0);
            }
        }
        const int lb = wave * 16;
        const float4 b2v = *(const float4*)(b2 + lb + q * 4);
        #pragma unroll
        for (int j = 0; j < 2; ++j) {
            const int m = j * 16 + c;
            #pragma unroll
            for (int rg = 0; rg < 4; ++rg) {
                const int l = lb + q * 4 + rg;
                latT[l * LAT_STRIDE + m] = sigmoidf(acc2[j][rg] + ((const float*)&b2v)[rg]);
            }
        }
    }
    __syncthreads();   // B4: latT complete; Hs dead -> mus writable

    // ================= stage 3a: tree routing =================
    {
        const int r = lane & 31;
        const int e = wave * 2 + (lane >> 5);
        if (e < E_NUM) {
            float mu[64];
            mu[0] = 1.0f;
            #pragma unroll
            for (int lev = 0; lev < 6; ++lev) {
                const int w = 1 << lev;
                #pragma unroll
                for (int i = w - 1; i >= 0; --i) {
                    float d = latT[phis[e * 64 + w + i] * LAT_STRIDE + r];
                    float m = mu[i];
                    mu[2 * i + 1] = m - m * d;
                    mu[2 * i]     = m * d;
                }
            }
            #pragma unroll
            for (int j8 = 0; j8 < 8; ++j8) {
                bf16x8 v;
                #pragma unroll
                for (int t = 0; t < 4; ++t) {
                    unsigned int p = pk2(mu[j8 * 8 + 2 * t], mu[j8 * 8 + 2 * t + 1]);
                    v[2 * t]     = (short)(p & 0xFFFF);
                    v[2 * t + 1] = (short)(p >> 16);
                }
                *((bf16x8*)&mus[r * MU_STRIDE + e * 64 + j8 * 8]) = v;
            }
        }
    }
    __syncthreads();   // B5: mus complete

    // ================= stage 3b: out[m][o] = sum_k mus[m][k] * piT[o][k] =================
    if (wave < 2) {
        const int mt = wave;
        bf16x8 pfrag[10];
        #pragma unroll
        for (int ks = 0; ks < 10; ++ks)
            pfrag[ks] = *(const bf16x8*)(piTf + ((size_t)ks * 64 + lane) * 8);
        f32x4 acc3 = (f32x4){0.f, 0.f, 0.f, 0.f};
        #pragma unroll
        for (int ks = 0; ks < 10; ++ks) {
            bf16x8 af = *((const bf16x8*)&mus[(mt * 16 + c) * MU_STRIDE + ks * 32 + q * 8]);
            acc3 = __builtin_amdgcn_mfma_f32_16x16x32_bf16(af, pfrag[ks], acc3, 0, 0, 0);
        }
        #pragma unroll
        for (int rg = 0; rg < 4; ++rg) {
            const int m = mt * 16 + q * 4 + rg;
            out[(size_t)(row0 + m) * O_DIM + c] = acc3[rg];
        }
    }
}

extern "C" void kernel_launch(void* const* d_in, const int* in_sizes, int n_in,
                              void* d_out, int out_size, void* d_ws, size_t ws_size,
                              hipStream_t stream) {
    (void)in_sizes; (void)n_in; (void)out_size; (void)ws_size;
    const float* X  = (const float*)d_in[0];
    const float* W1 = (const float*)d_in[1];
    const float* b1 = (const float*)d_in[2];
    const float* W2 = (const float*)d_in[3];
    const float* b2 = (const float*)d_in[4];
    const int*   phi = (const int*)d_in[5];
    const float* pi  = (const float*)d_in[6];
    float* out = (float*)d_out;

    unsigned short* W1f  = (unsigned short*)d_ws;                           // 196608 B
    unsigned short* W2f  = (unsigned short*)((char*)d_ws + 196608);         //  49152 B
    unsigned short* piTf = (unsigned short*)((char*)d_ws + 196608 + 49152); //  10240 B

    prep_kernel<<<121, 256, 0, stream>>>(W1, W2, pi, W1f, W2f, piTf);

    const int nblocks = 131072 / BM;  // 4096
    fused_kernel<<<nblocks, 256, 0, stream>>>(X, W1f, b1, W2f, b2, phi, piTf, out);
}